// Round 2
// baseline (815.223 us; speedup 1.0000x reference)
//
#include <hip/hip_runtime.h>
#include <cstdint>
#include <cstddef>

#define D_DIM 128

typedef __attribute__((ext_vector_type(8))) __bf16 bf16x8;
typedef __attribute__((ext_vector_type(4))) float f32x4;

// ---------------------------------------------------------------------------
// Fully fused: out[n,c] = ||x_n||^2 + ||w_c||^2 - 2 <x_n, w_c>
//
// Single kernel, no workspace, no LDS, no barriers. Each 256-thread block
// owns a 128x128 output tile. Fragments are loaded as fp32 straight from
// global (x-tile 64 KB is L2-hot: with XCD-grouped mapping the 8 c-blocks
// sharing it run on the same XCD; w is 512 KB, L2-resident), converted to
// bf16 in-register (hardware v_cvt, RNE), and the squared norms are
// computed from the same registers: each lane's 32-element partial per row
// is quad-reduced with two shfl_xor. With the operand-swapped MFMA
// (mfma(b,a): D row = c-local = quad*4+reg, D col = m-local = lane16),
// the row norm each lane needs IS its own lane16 row, and the 4 column
// norms come from one width-16 shuffle each.
//
// Two-deep load pipeline (32 x 16B loads in flight) hides L2 latency;
// epilogue streams the fp32 tile with non-temporal dwordx4 stores.
// ---------------------------------------------------------------------------
__global__ __launch_bounds__(256, 2) void rbf_fused(
    const float* __restrict__ x, const float* __restrict__ w,
    float* __restrict__ out, int C_total, int tiles_c, int tiles_m)
{
    // --- XCD-grouped tile mapping (hardware XCD = linear blockIdx % 8) ---
    int ty, tx;
    {
        const int bid = blockIdx.x;
        if ((tiles_m & 7) == 0) {
            const int xcd = bid & 7;
            const int i   = bid >> 3;
            const int iy  = i / tiles_c;
            ty = xcd * (tiles_m >> 3) + iy;   // contiguous m-range per XCD
            tx = i - iy * tiles_c;            // c-tile fastest -> x-tile L2 reuse
        } else {
            ty = bid / tiles_c;
            tx = bid - ty * tiles_c;
        }
    }

    const int lane   = threadIdx.x & 63;
    const int wave   = threadIdx.x >> 6;
    const int lane16 = lane & 15;
    const int quad   = lane >> 4;
    const int wm = (wave & 1) * 64;
    const int wc = (wave >> 1) * 64;

    const long m0 = (long)ty * 128;
    const long c0 = (long)tx * 128;

    // lane holds row (lane16) of each 16-row sub-tile, k = quad*8 + 0..7
    const float* aptr = x + (size_t)(m0 + wm + lane16) * D_DIM + quad * 8;
    const float* bptr = w + (size_t)(c0 + wc + lane16) * D_DIM + quad * 8;

    f32x4 acc[4][4];   // acc[ct][mt]
    #pragma unroll
    for (int i = 0; i < 4; ++i)
        #pragma unroll
        for (int j = 0; j < 4; ++j)
            acc[i][j] = (f32x4){0.f, 0.f, 0.f, 0.f};

    float sa[4] = {0.f, 0.f, 0.f, 0.f};   // partial ||x_row||^2 (lane's 32 elems)
    float sb[4] = {0.f, 0.f, 0.f, 0.f};   // partial ||w_row||^2

#define LOADC(AF, BF, KC) do {                                              \
        _Pragma("unroll")                                                   \
        for (int t = 0; t < 4; ++t) {                                       \
            const float* pa = aptr + (size_t)t * 16 * D_DIM + (KC) * 32;    \
            AF[t][0] = *reinterpret_cast<const float4*>(pa);                \
            AF[t][1] = *reinterpret_cast<const float4*>(pa + 4);            \
            const float* pb = bptr + (size_t)t * 16 * D_DIM + (KC) * 32;    \
            BF[t][0] = *reinterpret_cast<const float4*>(pb);                \
            BF[t][1] = *reinterpret_cast<const float4*>(pb + 4);            \
        }                                                                   \
    } while (0)

#define CVT8(DST, LO, HI) do {                                              \
        DST[0] = (__bf16)(LO).x; DST[1] = (__bf16)(LO).y;                   \
        DST[2] = (__bf16)(LO).z; DST[3] = (__bf16)(LO).w;                   \
        DST[4] = (__bf16)(HI).x; DST[5] = (__bf16)(HI).y;                   \
        DST[6] = (__bf16)(HI).z; DST[7] = (__bf16)(HI).w;                   \
    } while (0)

#define PROCESS(AF, BF) do {                                                \
        bf16x8 a8[4], b8[4];                                                \
        _Pragma("unroll")                                                   \
        for (int t = 0; t < 4; ++t) {                                       \
            float4 lo = AF[t][0], hi = AF[t][1];                            \
            sa[t] += lo.x*lo.x + lo.y*lo.y + lo.z*lo.z + lo.w*lo.w          \
                   + hi.x*hi.x + hi.y*hi.y + hi.z*hi.z + hi.w*hi.w;         \
            CVT8(a8[t], lo, hi);                                            \
            lo = BF[t][0]; hi = BF[t][1];                                   \
            sb[t] += lo.x*lo.x + lo.y*lo.y + lo.z*lo.z + lo.w*lo.w          \
                   + hi.x*hi.x + hi.y*hi.y + hi.z*hi.z + hi.w*hi.w;         \
            CVT8(b8[t], lo, hi);                                            \
        }                                                                   \
        _Pragma("unroll")                                                   \
        for (int ct = 0; ct < 4; ++ct)                                      \
            _Pragma("unroll")                                               \
            for (int mt = 0; mt < 4; ++mt)                                  \
                acc[ct][mt] = __builtin_amdgcn_mfma_f32_16x16x32_bf16(      \
                    b8[ct], a8[mt], acc[ct][mt], 0, 0, 0);                  \
    } while (0)

    // --- K loop: 4 chunks of k=32, two-deep load pipeline ---
    float4 A0[4][2], B0[4][2], A1[4][2], B1[4][2];
    LOADC(A0, B0, 0);
    LOADC(A1, B1, 1);
    PROCESS(A0, B0);
    LOADC(A0, B0, 2);
    PROCESS(A1, B1);
    LOADC(A1, B1, 3);
    PROCESS(A0, B0);
    PROCESS(A1, B1);

#undef LOADC
#undef CVT8
#undef PROCESS

    // --- finish norms: reduce across the 4 quads (lanes lane16 + {0,16,32,48}) ---
    #pragma unroll
    for (int t = 0; t < 4; ++t) {
        sa[t] += __shfl_xor(sa[t], 16, 64);
        sa[t] += __shfl_xor(sa[t], 32, 64);
        sb[t] += __shfl_xor(sb[t], 16, 64);
        sb[t] += __shfl_xor(sb[t], 32, 64);
    }
    // row norm for the epilogue: lane's own lane16 row -> sa[mt] directly.
    // col norms: within each 16-lane group, lane j holds col (ct*16+j);
    // lane (quad) needs cols quad*4 + 0..3.
    f32x4 wsv[4];
    #pragma unroll
    for (int ct = 0; ct < 4; ++ct)
        #pragma unroll
        for (int r = 0; r < 4; ++r)
            wsv[ct][r] = __shfl(sb[ct], quad * 4 + r, 16);

    // --- epilogue: D row = c-local = quad*4 + reg, D col = m-local = lane16 ---
    #pragma unroll
    for (int mt = 0; mt < 4; ++mt) {
        const long m = m0 + wm + mt * 16 + lane16;
        float* orow = out + m * (long)C_total + c0 + wc + quad * 4;
        #pragma unroll
        for (int ct = 0; ct < 4; ++ct) {
            f32x4 v;
            #pragma unroll
            for (int r = 0; r < 4; ++r)
                v[r] = sa[mt] + wsv[ct][r] - 2.0f * acc[ct][mt][r];
            __builtin_nontemporal_store(v, reinterpret_cast<f32x4*>(orow + ct * 16));
        }
    }
}

extern "C" void kernel_launch(void* const* d_in, const int* in_sizes, int n_in,
                              void* d_out, int out_size, void* d_ws, size_t ws_size,
                              hipStream_t stream) {
    const float* x = (const float*)d_in[0];
    const float* w = (const float*)d_in[1];
    float* out = (float*)d_out;

    const int N = in_sizes[0] / D_DIM;   // 131072
    const int C = in_sizes[1] / D_DIM;   // 1024

    const int tiles_m = N / 128;          // 1024
    const int tiles_c = C / 128;          // 8
    rbf_fused<<<dim3(tiles_m * tiles_c), 256, 0, stream>>>(
        x, w, out, C, tiles_c, tiles_m);
}